// Round 11
// baseline (274.055 us; speedup 1.0000x reference)
//
#include <hip/hip_runtime.h>

// LNKillingRelu: out = where(kf<=0, x, x + kf*d)
//   d[b,g,k,n]  = sum_f W[g,f] x[b,f,k,n]          (bf16 MFMA GEMM, K=512)
//   kf[b,g,n]   = sum_{k,l} x[b,g,k,n] G[k,l] d[b,g,l,n]   (fp32, G = sl3 Killing)
// x: [8,512,8,2048] f32, W: [512,512] f32, out same shape as x.
//
// R11: full-g block (x staged once) built ONLY from proven-safe pieces after
// R10's post-timing race (new sync template w/ reg-prefetch vmcnt ledger):
//  - A (W) fragments read DIRECTLY from L2-resident packed wp (R8-proven
//    correct; 512KB, per-CU 32KB/iter from L2) -> no A staging, no A sync.
//  - B staged via global_load_lds into 2-buffer LDS with plain __syncthreads
//    (full drain; B(kt+1) issued at loop TOP so exposure = one compute
//    window ~1500cy > 900cy HBM latency; R2/R3 failed this only at ~300cy).
//  - epilogue x as bf16 from xp (R5-proven, absmax 4.0) -> -268MB HBM.
//  16 waves x 32 g-rows, acc[2][8]=64 regs, LDS 16KB, sync = __syncthreads only.

typedef short bf16x8 __attribute__((ext_vector_type(8)));
typedef float f32x4 __attribute__((ext_vector_type(4)));

__device__ __forceinline__ unsigned short f2bf(float f) {
  unsigned int u = __float_as_uint(f);
  u += 0x7fffu + ((u >> 16) & 1u);   // round-to-nearest-even
  return (unsigned short)(u >> 16);
}

__device__ __forceinline__ float bfu(unsigned short u) {
  return __uint_as_float(((unsigned int)u) << 16);
}

__device__ __forceinline__ void gload16(const void* g, void* l) {
  typedef const __attribute__((address_space(1))) unsigned int* gp_t;
  typedef __attribute__((address_space(3))) unsigned int* lp_t;
  __builtin_amdgcn_global_load_lds((gp_t)g, (lp_t)l, 16, 0, 0);
}

// ---------------- prepass: pack x -> bf16 tiles (128 MiB) ----------------
// chunk cid = (((b*128+nt)*16+kt)*4+kg)*128 + c ; element j: f = kt*32+kg*8+j,
// k = c>>4, n = nt*16 + (c&15). Per (b,nt,kt): one 8KB LDS-ready tile.
// [R5/R6-proven layout]
__global__ __launch_bounds__(256) void prepack_x(const float* __restrict__ x,
                                                 short* __restrict__ xp) {
  const int cid = blockIdx.x * 256 + threadIdx.x;    // 8,388,608 chunks
  const int c = cid & 127;
  int t = cid >> 7;
  const int kg = t & 3;  t >>= 2;
  const int kt = t & 15; t >>= 4;
  const int nt = t & 127; t >>= 7;
  const int b = t;
  const int f0 = kt * 32 + kg * 8;
  const float* src = x + ((size_t)(b * 512 + f0) * 8 + (c >> 4)) * 2048
                       + nt * 16 + (c & 15);
  bf16x8 v;
#pragma unroll
  for (int j = 0; j < 8; ++j) v[j] = (short)f2bf(src[(size_t)j * 16384]);
  *(bf16x8*)&xp[(size_t)cid * 8] = v;
}

// ---------------- prepass: pack W -> bf16 (512 KB) [R9-proven layout] -------
// chunk cid = (kt*4+kg)*512 + row ; elems j=0..7 -> f = kt*32 + kg*8 + j
__global__ __launch_bounds__(256) void prepack_w(const float* __restrict__ W,
                                                 short* __restrict__ wp) {
  const int cid = blockIdx.x * 256 + threadIdx.x;    // 32768 chunks
  const int row  = cid & 511;
  const int kgkt = cid >> 9;
  const int kg = kgkt & 3;
  const int kt = kgkt >> 2;
  const float* src = W + (size_t)row * 512 + kt * 32 + kg * 8;
  bf16x8 v;
#pragma unroll
  for (int j = 0; j < 8; ++j) v[j] = (short)f2bf(src[j]);
  *(bf16x8*)&wp[(size_t)cid * 8] = v;
}

// ---------------- main fused GEMM + Killing epilogue ----------------
__global__ __launch_bounds__(1024, 4) void lnkill_fullg2(
    const short* __restrict__ xp, const short* __restrict__ wp,
    float* __restrict__ out) {
  __shared__ __align__(16) short ldsB[2][4096];   // x tile: [kg(4)][c(128)][8]

  const int tid   = threadIdx.x;
  const int lane  = tid & 63;
  const int w     = tid >> 6;      // wave 0..15; owns g-rows w*32..w*32+31
  const int klane = lane >> 4;     // kg 0..3
  const int li    = lane & 15;

  const int bid = blockIdx.x;      // 0..1023 (no cross-block x sharing)
  const int nt  = bid & 127;
  const int b   = bid >> 7;
  const int n0  = nt * 16;

  const short* xpt = xp + ((size_t)(b * 128 + nt) * 16) * 4096;  // region, shorts

  f32x4 acc[2][8] = {};            // [fm][fn]; fn == k plane

  // prologue: stage B(0) (waves 0..7, chunk tid; dest linear = chunk order)
  if (tid < 512) gload16(xpt + (size_t)tid * 8, &ldsB[0][tid * 8]);
  __syncthreads();

#pragma unroll
  for (int kt = 0; kt < 16; ++kt) {
    // issue B(kt+1) at loop TOP -> drain exposure at the bottom syncthreads
    // is one full compute window. Write target buf (kt+1)&1 was read at
    // compute(kt-1), complete before syncthreads(kt-1) < this issue. Safe.
    if (kt < 15 && tid < 512)
      gload16(xpt + (size_t)(kt + 1) * 4096 + (size_t)tid * 8,
              &ldsB[(kt + 1) & 1][tid * 8]);

    // A fragments straight from L2-resident wp (no staging, no sync):
    // chunk = (kt*4+klane)*512 + w*32 + fm*16 + li
    const short* wt = wp + ((size_t)(kt * 4 + klane) * 512 + w * 32 + li) * 8;
    bf16x8 afr0 = *(const bf16x8*)(wt);
    bf16x8 afr1 = *(const bf16x8*)(wt + 128);   // +16 rows = +16 chunks

    const short* Bc = ldsB[kt & 1];
    bf16x8 bfr[8];
#pragma unroll
    for (int fn = 0; fn < 8; ++fn)
      bfr[fn] = *(const bf16x8*)&Bc[(klane * 128 + fn * 16 + li) * 8];

#pragma unroll
    for (int fn = 0; fn < 8; ++fn)
      acc[0][fn] = __builtin_amdgcn_mfma_f32_16x16x32_bf16(afr0, bfr[fn],
                                                           acc[0][fn], 0, 0, 0);
#pragma unroll
    for (int fn = 0; fn < 8; ++fn)
      acc[1][fn] = __builtin_amdgcn_mfma_f32_16x16x32_bf16(afr1, bfr[fn],
                                                           acc[1][fn], 0, 0, 0);

    if (kt < 15) __syncthreads();   // vmcnt(0)+lgkm(0)+barrier: B(kt+1) landed
  }

  // ---- epilogue: kf (Killing Gram) + branch + store; x as bf16 from xp ----
  // x[b,g,k,n0+li] in xp: tile=g>>5=w, chunk=(fm*2+(klane>>1))*128 + k*16+li,
  // elem j=(klane&1)*4+r.  [R5-proven bf16-epilogue accuracy]
  const unsigned short* xu = (const unsigned short*)xpt;
#pragma unroll
  for (int fm = 0; fm < 2; ++fm) {
#pragma unroll
    for (int r = 0; r < 4; ++r) {
      const int g = w * 32 + fm * 16 + klane * 4 + r;
      const size_t base = ((size_t)(b * 512 + g)) * 16384 + n0 + li;
      const size_t ch0 = (size_t)w * 4096
                       + (size_t)((fm * 2 + (klane >> 1)) * 128 + li) * 8
                       + (klane & 1) * 4 + r;
      float xk[8];
#pragma unroll
      for (int k = 0; k < 8; ++k) xk[k] = bfu(xu[ch0 + (size_t)k * 128]);
      // c_l = (G x)_l ; G: 12@(0,0),(4,4); -6@(0,4); 6@{1,3},{2,6},{5,7}
      const float c0 = 12.f * xk[0] - 6.f * xk[4];
      const float c4 = 12.f * xk[4] - 6.f * xk[0];
      const float c1 = 6.f * xk[3];
      const float c2 = 6.f * xk[6];
      const float c3 = 6.f * xk[1];
      const float c5 = 6.f * xk[7];
      const float c6 = 6.f * xk[2];
      const float c7 = 6.f * xk[5];
      const float kf = c0 * acc[fm][0][r] + c1 * acc[fm][1][r]
                     + c2 * acc[fm][2][r] + c3 * acc[fm][3][r]
                     + c4 * acc[fm][4][r] + c5 * acc[fm][5][r]
                     + c6 * acc[fm][6][r] + c7 * acc[fm][7][r];
#pragma unroll
      for (int k = 0; k < 8; ++k) {
        const float o = (kf <= 0.f) ? xk[k] : fmaf(kf, acc[fm][k][r], xk[k]);
        out[base + (size_t)k * 2048] = o;
      }
    }
  }
}

// ---------------- fallback: proven R2 kernel (ws too small) ----------------
__global__ __launch_bounds__(512, 4) void lnkill_fused(
    const float* __restrict__ x, const float* __restrict__ W,
    float* __restrict__ out) {
  __shared__ __align__(16) short ldsA[2][4096];
  __shared__ __align__(16) short ldsB[2][4096];

  const int tid  = threadIdx.x;
  const int lane = tid & 63;
  const int w    = tid >> 6;

  const int bid = blockIdx.x;
  const int l   = (bid & 7) * 512 + (bid >> 3);
  const int gt  = l & 3;
  const int nt  = (l >> 2) & 127;
  const int b   = l >> 9;
  const int g0  = gt * 128;
  const int n0  = nt * 16;

  const int cm = tid & 127;
  const int fg = tid >> 7;
  const float* xs   = x + (((size_t)(b * 512 + fg * 8)) * 8 + (cm >> 4)) * 2048
                        + n0 + (cm & 15);
  const float* Wrow = W + (size_t)(g0 + cm) * 512 + fg * 8;

  f32x4 acc[8] = {};

  {
    float xv[8];
#pragma unroll
    for (int j = 0; j < 8; ++j) xv[j] = xs[(size_t)j * 16384];
    float4 wv[2];
    const float4* wpp = (const float4*)Wrow;
    wv[0] = wpp[0]; wv[1] = wpp[1];
    const float* wf = (const float*)wv;
    bf16x8 vb, va;
#pragma unroll
    for (int j = 0; j < 8; ++j) {
      vb[j] = (short)f2bf(xv[j]);
      va[j] = (short)f2bf(wf[j]);
    }
    *(bf16x8*)&ldsB[0][(fg * 128 + cm) * 8] = vb;
    *(bf16x8*)&ldsA[0][(fg * 128 + cm) * 8] = va;
  }
  __syncthreads();

  const int klane = lane >> 4;
  const int li    = lane & 15;

  for (int kt = 0; kt < 16; ++kt) {
    const int cur = kt & 1;
    float xv[8];
    float4 wv[2];
    if (kt < 15) {
      const float* xpn = xs + (size_t)(kt + 1) * 32 * 16384;
#pragma unroll
      for (int j = 0; j < 8; ++j) xv[j] = xpn[(size_t)j * 16384];
      const float4* wpp = (const float4*)(Wrow + (kt + 1) * 32);
      wv[0] = wpp[0]; wv[1] = wpp[1];
    }
    {
      const short* Ac = ldsA[cur];
      const short* Bc = ldsB[cur];
      bf16x8 afr = *(const bf16x8*)&Ac[(klane * 128 + w * 16 + li) * 8];
#pragma unroll
      for (int fn = 0; fn < 8; ++fn) {
        bf16x8 bfr = *(const bf16x8*)&Bc[(klane * 128 + fn * 16 + li) * 8];
        acc[fn] = __builtin_amdgcn_mfma_f32_16x16x32_bf16(afr, bfr, acc[fn], 0, 0, 0);
      }
    }
    if (kt < 15) {
      const int nxt = cur ^ 1;
      const float* wf = (const float*)wv;
      bf16x8 vb, va;
#pragma unroll
      for (int j = 0; j < 8; ++j) {
        vb[j] = (short)f2bf(xv[j]);
        va[j] = (short)f2bf(wf[j]);
      }
      __syncthreads();
      *(bf16x8*)&ldsB[nxt][(fg * 128 + cm) * 8] = vb;
      *(bf16x8*)&ldsA[nxt][(fg * 128 + cm) * 8] = va;
      __syncthreads();
    }
  }

#pragma unroll
  for (int r = 0; r < 4; ++r) {
    const int g = g0 + w * 16 + klane * 4 + r;
    const size_t base = ((size_t)(b * 512 + g)) * 16384 + n0 + li;
    float xk[8];
#pragma unroll
    for (int k = 0; k < 8; ++k) xk[k] = x[base + (size_t)k * 2048];
    const float c0 = 12.f * xk[0] - 6.f * xk[4];
    const float c4 = 12.f * xk[4] - 6.f * xk[0];
    const float c1 = 6.f * xk[3];
    const float c2 = 6.f * xk[6];
    const float c3 = 6.f * xk[1];
    const float c5 = 6.f * xk[7];
    const float c6 = 6.f * xk[2];
    const float c7 = 6.f * xk[5];
    const float kf = c0 * acc[0][r] + c1 * acc[1][r]
                   + c2 * acc[2][r] + c3 * acc[3][r]
                   + c4 * acc[4][r] + c5 * acc[5][r]
                   + c6 * acc[6][r] + c7 * acc[7][r];
#pragma unroll
    for (int k = 0; k < 8; ++k) {
      const float o = (kf <= 0.f) ? xk[k] : fmaf(kf, acc[k][r], xk[k]);
      out[base + (size_t)k * 2048] = o;
    }
  }
}

extern "C" void kernel_launch(void* const* d_in, const int* in_sizes, int n_in,
                              void* d_out, int out_size, void* d_ws, size_t ws_size,
                              hipStream_t stream) {
  const float* x = (const float*)d_in[0];
  const float* W = (const float*)d_in[1];
  float* out = (float*)d_out;

  const size_t need = (size_t)512 * 1024 + (size_t)8388608 * 16;  // 0.5MB + 128MiB
  if (ws_size >= need) {
    short* wp = (short*)d_ws;                       // 512 KB packed W
    short* xp = (short*)d_ws + 262144;              // 128 MiB packed x
    prepack_w<<<dim3(128),   dim3(256), 0, stream>>>(W, wp);
    prepack_x<<<dim3(32768), dim3(256), 0, stream>>>(x, xp);
    // 1024 blocks: 128 nt x 8 b ; 1024 thr (16 waves x 32 g-rows, full 512 g)
    lnkill_fullg2<<<dim3(1024), dim3(1024), 0, stream>>>(xp, wp, out);
  } else {
    lnkill_fused<<<dim3(4096), dim3(512), 0, stream>>>(x, W, out);
  }
}

// Round 12
// 244.798 us; speedup vs baseline: 1.1195x; 1.1195x over previous
//
#include <hip/hip_runtime.h>

// LNKillingRelu: out = where(kf<=0, x, x + kf*d)
//   d[b,g,k,n]  = sum_f W[g,f] x[b,f,k,n]          (bf16 MFMA GEMM, K=512)
//   kf[b,g,n]   = sum_{k,l} x[b,g,k,n] G[k,l] d[b,g,l,n]   (fp32, G = sl3 Killing)
// x: [8,512,8,2048] f32, W: [512,512] f32, out same shape as x.
//
// R12 = R11's proven loop skeleton (full-g block, A fragments direct from
// L2-resident packed W, double-buffered B in LDS, ONE full __syncthreads per
// iter) with x staged DIRECTLY from f32 (no 80us prepack_x, -134MB net HBM):
//   per iter: [cvt rB(kt+1) -> ds_write buf^1] [issue B(kt+2) loads]
//             [compute kt: A-direct + B ds_read + 16 MFMA] [syncthreads]
//   - cvt's implicit vmcnt wait is a NO-OP: its regs were drained by the
//     PREVIOUS iteration's syncthreads (no counted-vmcnt ledger -> no R10
//     race class, no R9 depth collapse).
//   - B(kt+2) issued before compute -> drain exposure = one compute window.
//   - rB[2][4] statically indexed in fully unrolled loop (no scratch).
//   epilogue: R6-proven coalesced f32 x re-read (slice is L2-warm).

typedef short bf16x8 __attribute__((ext_vector_type(8)));
typedef short bf16x4 __attribute__((ext_vector_type(4)));
typedef float f32x4 __attribute__((ext_vector_type(4)));

__device__ __forceinline__ unsigned short f2bf(float f) {
  unsigned int u = __float_as_uint(f);
  u += 0x7fffu + ((u >> 16) & 1u);   // round-to-nearest-even
  return (unsigned short)(u >> 16);
}

// ---------------- prepass: pack W -> bf16 (512 KB) [R9/R11-proven] ----------
// chunk cid = (kt*4+kg)*512 + row ; elems j=0..7 -> f = kt*32 + kg*8 + j
__global__ __launch_bounds__(256) void prepack_w(const float* __restrict__ W,
                                                 short* __restrict__ wp) {
  const int cid = blockIdx.x * 256 + threadIdx.x;    // 32768 chunks
  const int row  = cid & 511;
  const int kgkt = cid >> 9;
  const int kg = kgkt & 3;
  const int kt = kgkt >> 2;
  const float* src = W + (size_t)row * 512 + kt * 32 + kg * 8;
  bf16x8 v;
#pragma unroll
  for (int j = 0; j < 8; ++j) v[j] = (short)f2bf(src[j]);
  *(bf16x8*)&wp[(size_t)cid * 8] = v;
}

// ---------------- main fused GEMM + Killing epilogue ----------------
__global__ __launch_bounds__(1024, 4) void lnkill_fullg3(
    const float* __restrict__ x, const short* __restrict__ wp,
    float* __restrict__ out) {
  __shared__ __align__(16) short ldsB[2][4096];   // x tile: [kg(4)][c(128)][8]

  const int tid   = threadIdx.x;
  const int lane  = tid & 63;
  const int w     = tid >> 6;      // wave 0..15; owns g-rows w*32..w*32+31
  const int klane = lane >> 4;     // kg 0..3
  const int li    = lane & 15;

  const int bid = blockIdx.x;      // 0..1023 (no cross-block x sharing)
  const int nt  = bid & 127;
  const int b   = bid >> 7;
  const int n0  = nt * 16;

  // x staging map: cm = c-col (k*16+nn), fg = f-subgroup of 4
  //   f = kt*32 + (fg>>1)*8 + (fg&1)*4 + jj ; k = cm>>4 ; n = n0 + (cm&15)
  const int cm = tid & 127;
  const int fg = tid >> 7;         // 0..7
  const int kgs = fg >> 1;         // kg of staged elems
  const int j0  = (fg & 1) * 4;
  const float* xs = x + (((size_t)(b * 512 + kgs * 8 + j0)) * 8 + (cm >> 4)) * 2048
                      + n0 + (cm & 15);
  const int bwr = (kgs * 128 + cm) * 8 + j0;      // B ds_write slot (bf16x4)

  f32x4 acc[2][8] = {};            // [fm][fn]; fn == k plane
  float rB[2][4];                  // staged-x regsets; B(t) in rB[t&1]

  // ---- prologue ----
  {
    float b0[4];
#pragma unroll
    for (int jj = 0; jj < 4; ++jj) b0[jj] = xs[(size_t)jj * 16384];      // B(0)
#pragma unroll
    for (int jj = 0; jj < 4; ++jj) rB[1][jj] = xs[(size_t)(32 + jj) * 16384]; // B(1)
    bf16x4 v;    // implicit wait covers b0 only (rB[1] stays in flight)
#pragma unroll
    for (int jj = 0; jj < 4; ++jj) v[jj] = (short)f2bf(b0[jj]);
    *(bf16x4*)&ldsB[0][bwr] = v;
  }
  __syncthreads();   // B(0) visible; B(1) regs landed

#pragma unroll
  for (int kt = 0; kt < 16; ++kt) {
    // 1) cvt B(kt+1) (regs drained by prev syncthreads) -> buf (kt+1)&1.
    //    Write target buf was read at compute(kt-1), before prev syncthreads.
    if (kt < 15) {
      bf16x4 v;
#pragma unroll
      for (int jj = 0; jj < 4; ++jj) v[jj] = (short)f2bf(rB[(kt + 1) & 1][jj]);
      *(bf16x4*)&ldsB[(kt + 1) & 1][bwr] = v;
    }
    // 2) issue B(kt+2) loads -> rB[kt&1] (drained at this iter's syncthreads;
    //    exposure = the compute window below)
    if (kt < 14) {
#pragma unroll
      for (int jj = 0; jj < 4; ++jj)
        rB[kt & 1][jj] = xs[(size_t)((kt + 2) * 32 + jj) * 16384];
    }

    // 3) compute tile kt: A direct from L2-resident wp, B from LDS
    //    A chunk = (kt*4+klane)*512 + w*32 + fm*16 + li
    const short* wt = wp + ((size_t)(kt * 4 + klane) * 512 + w * 32 + li) * 8;
    bf16x8 afr0 = *(const bf16x8*)(wt);
    bf16x8 afr1 = *(const bf16x8*)(wt + 128);   // +16 rows
    const short* Bc = ldsB[kt & 1];
    bf16x8 bfr[8];
#pragma unroll
    for (int fn = 0; fn < 8; ++fn)
      bfr[fn] = *(const bf16x8*)&Bc[(klane * 128 + fn * 16 + li) * 8];
#pragma unroll
    for (int fn = 0; fn < 8; ++fn)
      acc[0][fn] = __builtin_amdgcn_mfma_f32_16x16x32_bf16(afr0, bfr[fn],
                                                           acc[0][fn], 0, 0, 0);
#pragma unroll
    for (int fn = 0; fn < 8; ++fn)
      acc[1][fn] = __builtin_amdgcn_mfma_f32_16x16x32_bf16(afr1, bfr[fn],
                                                           acc[1][fn], 0, 0, 0);

    // 4) full drain + barrier: B(kt+2) regs landed; buf writes visible;
    //    WAR protection for next iter's ds_write into buf kt&1.
    if (kt < 15) __syncthreads();
  }

  // ---- epilogue: kf (fp32 x, Killing Gram) + branch + store [R6-proven] ----
  // D frag: col = li (nn), row-in-16 = klane*4 + r
#pragma unroll
  for (int fm = 0; fm < 2; ++fm) {
#pragma unroll
    for (int r = 0; r < 4; ++r) {
      const int g = w * 32 + fm * 16 + klane * 4 + r;
      const size_t base = ((size_t)(b * 512 + g)) * 16384 + n0 + li;
      float xk[8];
#pragma unroll
      for (int k = 0; k < 8; ++k) xk[k] = x[base + (size_t)k * 2048];
      // c_l = (G x)_l ; G: 12@(0,0),(4,4); -6@(0,4); 6@{1,3},{2,6},{5,7}
      const float c0 = 12.f * xk[0] - 6.f * xk[4];
      const float c4 = 12.f * xk[4] - 6.f * xk[0];
      const float c1 = 6.f * xk[3];
      const float c2 = 6.f * xk[6];
      const float c3 = 6.f * xk[1];
      const float c5 = 6.f * xk[7];
      const float c6 = 6.f * xk[2];
      const float c7 = 6.f * xk[5];
      const float kf = c0 * acc[fm][0][r] + c1 * acc[fm][1][r]
                     + c2 * acc[fm][2][r] + c3 * acc[fm][3][r]
                     + c4 * acc[fm][4][r] + c5 * acc[fm][5][r]
                     + c6 * acc[fm][6][r] + c7 * acc[fm][7][r];
#pragma unroll
      for (int k = 0; k < 8; ++k) {
        const float o = (kf <= 0.f) ? xk[k] : fmaf(kf, acc[fm][k][r], xk[k]);
        out[base + (size_t)k * 2048] = o;
      }
    }
  }
}

// ---------------- fallback: proven R2 kernel (ws too small) ----------------
__global__ __launch_bounds__(512, 4) void lnkill_fused(
    const float* __restrict__ x, const float* __restrict__ W,
    float* __restrict__ out) {
  __shared__ __align__(16) short ldsA[2][4096];
  __shared__ __align__(16) short ldsB[2][4096];

  const int tid  = threadIdx.x;
  const int lane = tid & 63;
  const int w    = tid >> 6;

  const int bid = blockIdx.x;
  const int l   = (bid & 7) * 512 + (bid >> 3);
  const int gt  = l & 3;
  const int nt  = (l >> 2) & 127;
  const int b   = l >> 9;
  const int g0  = gt * 128;
  const int n0  = nt * 16;

  const int cm = tid & 127;
  const int fg = tid >> 7;
  const float* xs   = x + (((size_t)(b * 512 + fg * 8)) * 8 + (cm >> 4)) * 2048
                        + n0 + (cm & 15);
  const float* Wrow = W + (size_t)(g0 + cm) * 512 + fg * 8;

  f32x4 acc[8] = {};

  {
    float xv[8];
#pragma unroll
    for (int j = 0; j < 8; ++j) xv[j] = xs[(size_t)j * 16384];
    float4 wv[2];
    const float4* wpp = (const float4*)Wrow;
    wv[0] = wpp[0]; wv[1] = wpp[1];
    const float* wf = (const float*)wv;
    bf16x8 vb, va;
#pragma unroll
    for (int j = 0; j < 8; ++j) {
      vb[j] = (short)f2bf(xv[j]);
      va[j] = (short)f2bf(wf[j]);
    }
    *(bf16x8*)&ldsB[0][(fg * 128 + cm) * 8] = vb;
    *(bf16x8*)&ldsA[0][(fg * 128 + cm) * 8] = va;
  }
  __syncthreads();

  const int klane = lane >> 4;
  const int li    = lane & 15;

  for (int kt = 0; kt < 16; ++kt) {
    const int cur = kt & 1;
    float xv[8];
    float4 wv[2];
    if (kt < 15) {
      const float* xpn = xs + (size_t)(kt + 1) * 32 * 16384;
#pragma unroll
      for (int j = 0; j < 8; ++j) xv[j] = xpn[(size_t)j * 16384];
      const float4* wpp = (const float4*)(Wrow + (kt + 1) * 32);
      wv[0] = wpp[0]; wv[1] = wpp[1];
    }
    {
      const short* Ac = ldsA[cur];
      const short* Bc = ldsB[cur];
      bf16x8 afr = *(const bf16x8*)&Ac[(klane * 128 + w * 16 + li) * 8];
#pragma unroll
      for (int fn = 0; fn < 8; ++fn) {
        bf16x8 bfr = *(const bf16x8*)&Bc[(klane * 128 + fn * 16 + li) * 8];
        acc[fn] = __builtin_amdgcn_mfma_f32_16x16x32_bf16(afr, bfr, acc[fn], 0, 0, 0);
      }
    }
    if (kt < 15) {
      const int nxt = cur ^ 1;
      const float* wf = (const float*)wv;
      bf16x8 vb, va;
#pragma unroll
      for (int j = 0; j < 8; ++j) {
        vb[j] = (short)f2bf(xv[j]);
        va[j] = (short)f2bf(wf[j]);
      }
      __syncthreads();
      *(bf16x8*)&ldsB[nxt][(fg * 128 + cm) * 8] = vb;
      *(bf16x8*)&ldsA[nxt][(fg * 128 + cm) * 8] = va;
      __syncthreads();
    }
  }

#pragma unroll
  for (int r = 0; r < 4; ++r) {
    const int g = g0 + w * 16 + klane * 4 + r;
    const size_t base = ((size_t)(b * 512 + g)) * 16384 + n0 + li;
    float xk[8];
#pragma unroll
    for (int k = 0; k < 8; ++k) xk[k] = x[base + (size_t)k * 2048];
    const float c0 = 12.f * xk[0] - 6.f * xk[4];
    const float c4 = 12.f * xk[4] - 6.f * xk[0];
    const float c1 = 6.f * xk[3];
    const float c2 = 6.f * xk[6];
    const float c3 = 6.f * xk[1];
    const float c5 = 6.f * xk[7];
    const float c6 = 6.f * xk[2];
    const float c7 = 6.f * xk[5];
    const float kf = c0 * acc[0][r] + c1 * acc[1][r]
                   + c2 * acc[2][r] + c3 * acc[3][r]
                   + c4 * acc[4][r] + c5 * acc[5][r]
                   + c6 * acc[6][r] + c7 * acc[7][r];
#pragma unroll
    for (int k = 0; k < 8; ++k) {
      const float o = (kf <= 0.f) ? xk[k] : fmaf(kf, acc[k][r], xk[k]);
      out[base + (size_t)k * 2048] = o;
    }
  }
}

extern "C" void kernel_launch(void* const* d_in, const int* in_sizes, int n_in,
                              void* d_out, int out_size, void* d_ws, size_t ws_size,
                              hipStream_t stream) {
  const float* x = (const float*)d_in[0];
  const float* W = (const float*)d_in[1];
  float* out = (float*)d_out;

  if (ws_size >= (size_t)524288) {
    short* wp = (short*)d_ws;                       // 512 KB packed W
    prepack_w<<<dim3(128), dim3(256), 0, stream>>>(W, wp);
    // 1024 blocks: 128 nt x 8 b ; 1024 thr (16 waves x 32 g-rows, full 512 g)
    lnkill_fullg3<<<dim3(1024), dim3(1024), 0, stream>>>(x, wp, out);
  } else {
    lnkill_fused<<<dim3(4096), dim3(512), 0, stream>>>(x, W, out);
  }
}

// Round 13
// 182.231 us; speedup vs baseline: 1.5039x; 1.3433x over previous
//
#include <hip/hip_runtime.h>

// LNKillingRelu: out = where(kf<=0, x, x + kf*d)
//   d[b,g,k,n]  = sum_f W[g,f] x[b,f,k,n]          (bf16 MFMA GEMM, K=512)
//   kf[b,g,n]   = sum_{k,l} x[b,g,k,n] G[k,l] d[b,g,l,n]   (fp32, G = sl3 Killing)
// x: [8,512,8,2048] f32, W: [512,512] f32, out same shape as x.
//
// R13 = R12 skeleton (full-g block, A direct from L2-resident packed W, one
// full __syncthreads per iter, reg-prefetch consumed only after a drain) with
// two counter-driven fixes:
//  (1) PERSISTENT 16-slot LDS x-tile (128 KB): tile kt staged into ldsX[kt]
//      (no aliasing -> WAR removed); epilogue reads x as bf16 from LDS
//      instead of re-fetching 268 MB f32 from HBM (R12 FETCH=528MB: the
//      256KB/block slice is L2-evicted between staging and epilogue).
//  (2) conflict-free staging writes: kgs=tid>>8, cm=(tid>>1)&127,
//      j0=(tid&1)*4 -> each thread's 8B write at byte tid*8 (dense; R12's
//      16B-stride bf16x4 writes caused the 1.05M bank-conflict cycles).
//      Loads stay coalesced: per wave-inst 2f x 2k x 16n = 4 x 64B lines.

typedef short bf16x8 __attribute__((ext_vector_type(8)));
typedef short bf16x4 __attribute__((ext_vector_type(4)));
typedef float f32x4 __attribute__((ext_vector_type(4)));

__device__ __forceinline__ unsigned short f2bf(float f) {
  unsigned int u = __float_as_uint(f);
  u += 0x7fffu + ((u >> 16) & 1u);   // round-to-nearest-even
  return (unsigned short)(u >> 16);
}

__device__ __forceinline__ float bfu(unsigned short u) {
  return __uint_as_float(((unsigned int)u) << 16);
}

// ---------------- prepass: pack W -> bf16 (512 KB) [R9/R11-proven] ----------
// chunk cid = (kt*4+kg)*512 + row ; elems j=0..7 -> f = kt*32 + kg*8 + j
__global__ __launch_bounds__(256) void prepack_w(const float* __restrict__ W,
                                                 short* __restrict__ wp) {
  const int cid = blockIdx.x * 256 + threadIdx.x;    // 32768 chunks
  const int row  = cid & 511;
  const int kgkt = cid >> 9;
  const int kg = kgkt & 3;
  const int kt = kgkt >> 2;
  const float* src = W + (size_t)row * 512 + kt * 32 + kg * 8;
  bf16x8 v;
#pragma unroll
  for (int j = 0; j < 8; ++j) v[j] = (short)f2bf(src[j]);
  *(bf16x8*)&wp[(size_t)cid * 8] = v;
}

// ---------------- main fused GEMM + Killing epilogue ----------------
__global__ __launch_bounds__(1024, 4) void lnkill_fullg4(
    const float* __restrict__ x, const short* __restrict__ wp,
    float* __restrict__ out) {
  // persistent x tile: slot kt = [kg(4)][c(128)][8 bf16], 8KB each, 128KB total
  __shared__ __align__(16) short ldsX[16][4096];

  const int tid   = threadIdx.x;
  const int lane  = tid & 63;
  const int w     = tid >> 6;      // wave 0..15; owns g-rows w*32..w*32+31
  const int klane = lane >> 4;     // kg 0..3
  const int li    = lane & 15;

  const int bid = blockIdx.x;      // 0..1023 (no cross-block x sharing)
  const int nt  = bid & 127;
  const int b   = bid >> 7;
  const int n0  = nt * 16;

  // staging map (conflict-free): thread writes 8B at byte tid*8 of the slot.
  //   kgs = tid>>8, cm = (tid>>1)&127, j0 = (tid&1)*4
  //   f = kt*32 + kgs*8 + j0 + jj ; k = cm>>4 ; n = n0 + (cm&15)
  const int kgs = tid >> 8;
  const int cm  = (tid >> 1) & 127;
  const int j0  = (tid & 1) * 4;
  const float* xs = x + (((size_t)(b * 512 + kgs * 8 + j0)) * 8 + (cm >> 4)) * 2048
                      + n0 + (cm & 15);
  const int bwr = tid * 4;         // shorts; == ((kgs*128+cm)*8 + j0)

  f32x4 acc[2][8] = {};            // [fm][fn]; fn == k plane
  float rB[2][4];                  // staged-x regsets; B(t) in rB[t&1]

  // ---- prologue ----
  {
    float b0[4];
#pragma unroll
    for (int jj = 0; jj < 4; ++jj) b0[jj] = xs[(size_t)jj * 16384];          // B(0)
#pragma unroll
    for (int jj = 0; jj < 4; ++jj) rB[1][jj] = xs[(size_t)(32 + jj) * 16384]; // B(1)
    bf16x4 v;    // implicit wait covers b0 only (rB[1] stays in flight)
#pragma unroll
    for (int jj = 0; jj < 4; ++jj) v[jj] = (short)f2bf(b0[jj]);
    *(bf16x4*)&ldsX[0][bwr] = v;
  }
  __syncthreads();   // B(0) visible; B(1) regs landed

#pragma unroll
  for (int kt = 0; kt < 16; ++kt) {
    // 1) cvt B(kt+1) (regs drained by prev syncthreads) -> slot kt+1
    //    (fresh slot, never read yet -> no WAR hazard at all)
    if (kt < 15) {
      bf16x4 v;
#pragma unroll
      for (int jj = 0; jj < 4; ++jj) v[jj] = (short)f2bf(rB[(kt + 1) & 1][jj]);
      *(bf16x4*)&ldsX[kt + 1][bwr] = v;
    }
    // 2) issue B(kt+2) loads -> rB[kt&1] (drained at this iter's syncthreads)
    if (kt < 14) {
#pragma unroll
      for (int jj = 0; jj < 4; ++jj)
        rB[kt & 1][jj] = xs[(size_t)((kt + 2) * 32 + jj) * 16384];
    }

    // 3) compute tile kt: A direct from L2-resident wp, B from slot kt
    const short* wt = wp + ((size_t)(kt * 4 + klane) * 512 + w * 32 + li) * 8;
    bf16x8 afr0 = *(const bf16x8*)(wt);
    bf16x8 afr1 = *(const bf16x8*)(wt + 128);   // +16 rows
    const short* Bc = ldsX[kt];
    bf16x8 bfr[8];
#pragma unroll
    for (int fn = 0; fn < 8; ++fn)
      bfr[fn] = *(const bf16x8*)&Bc[(klane * 128 + fn * 16 + li) * 8];
#pragma unroll
    for (int fn = 0; fn < 8; ++fn)
      acc[0][fn] = __builtin_amdgcn_mfma_f32_16x16x32_bf16(afr0, bfr[fn],
                                                           acc[0][fn], 0, 0, 0);
#pragma unroll
    for (int fn = 0; fn < 8; ++fn)
      acc[1][fn] = __builtin_amdgcn_mfma_f32_16x16x32_bf16(afr1, bfr[fn],
                                                           acc[1][fn], 0, 0, 0);

    // 4) full drain + barrier: B(kt+2) regs landed; slot kt+1 writes visible
    if (kt < 15) __syncthreads();
  }

  // ---- epilogue: kf (Killing Gram) + branch + store; x as bf16 from LDS ----
  // row g = w*32 + fm*16 + klane*4 + r lives in slot w:
  //   kg = fm*2 + (klane>>1), j = (klane&1)*4 + r, c = k*16 + li
  const unsigned short* xls = (const unsigned short*)&ldsX[w][0];
#pragma unroll
  for (int fm = 0; fm < 2; ++fm) {
#pragma unroll
    for (int r = 0; r < 4; ++r) {
      const int g = w * 32 + fm * 16 + klane * 4 + r;
      const size_t base = ((size_t)(b * 512 + g)) * 16384 + n0 + li;
      const int kgd = fm * 2 + (klane >> 1);
      const int jd  = (klane & 1) * 4 + r;
      float xk[8];
#pragma unroll
      for (int k = 0; k < 8; ++k)
        xk[k] = bfu(xls[(kgd * 128 + k * 16 + li) * 8 + jd]);
      // c_l = (G x)_l ; G: 12@(0,0),(4,4); -6@(0,4); 6@{1,3},{2,6},{5,7}
      const float c0 = 12.f * xk[0] - 6.f * xk[4];
      const float c4 = 12.f * xk[4] - 6.f * xk[0];
      const float c1 = 6.f * xk[3];
      const float c2 = 6.f * xk[6];
      const float c3 = 6.f * xk[1];
      const float c5 = 6.f * xk[7];
      const float c6 = 6.f * xk[2];
      const float c7 = 6.f * xk[5];
      const float kf = c0 * acc[fm][0][r] + c1 * acc[fm][1][r]
                     + c2 * acc[fm][2][r] + c3 * acc[fm][3][r]
                     + c4 * acc[fm][4][r] + c5 * acc[fm][5][r]
                     + c6 * acc[fm][6][r] + c7 * acc[fm][7][r];
#pragma unroll
      for (int k = 0; k < 8; ++k) {
        const float o = (kf <= 0.f) ? xk[k] : fmaf(kf, acc[fm][k][r], xk[k]);
        out[base + (size_t)k * 2048] = o;
      }
    }
  }
}

// ---------------- fallback: proven R2 kernel (ws too small) ----------------
__global__ __launch_bounds__(512, 4) void lnkill_fused(
    const float* __restrict__ x, const float* __restrict__ W,
    float* __restrict__ out) {
  __shared__ __align__(16) short ldsA[2][4096];
  __shared__ __align__(16) short ldsB[2][4096];

  const int tid  = threadIdx.x;
  const int lane = tid & 63;
  const int w    = tid >> 6;

  const int bid = blockIdx.x;
  const int l   = (bid & 7) * 512 + (bid >> 3);
  const int gt  = l & 3;
  const int nt  = (l >> 2) & 127;
  const int b   = l >> 9;
  const int g0  = gt * 128;
  const int n0  = nt * 16;

  const int cm = tid & 127;
  const int fg = tid >> 7;
  const float* xs   = x + (((size_t)(b * 512 + fg * 8)) * 8 + (cm >> 4)) * 2048
                        + n0 + (cm & 15);
  const float* Wrow = W + (size_t)(g0 + cm) * 512 + fg * 8;

  f32x4 acc[8] = {};

  {
    float xv[8];
#pragma unroll
    for (int j = 0; j < 8; ++j) xv[j] = xs[(size_t)j * 16384];
    float4 wv[2];
    const float4* wpp = (const float4*)Wrow;
    wv[0] = wpp[0]; wv[1] = wpp[1];
    const float* wf = (const float*)wv;
    bf16x8 vb, va;
#pragma unroll
    for (int j = 0; j < 8; ++j) {
      vb[j] = (short)f2bf(xv[j]);
      va[j] = (short)f2bf(wf[j]);
    }
    *(bf16x8*)&ldsB[0][(fg * 128 + cm) * 8] = vb;
    *(bf16x8*)&ldsA[0][(fg * 128 + cm) * 8] = va;
  }
  __syncthreads();

  const int klane = lane >> 4;
  const int li    = lane & 15;

  for (int kt = 0; kt < 16; ++kt) {
    const int cur = kt & 1;
    float xv[8];
    float4 wv[2];
    if (kt < 15) {
      const float* xpn = xs + (size_t)(kt + 1) * 32 * 16384;
#pragma unroll
      for (int j = 0; j < 8; ++j) xv[j] = xpn[(size_t)j * 16384];
      const float4* wpp = (const float4*)(Wrow + (kt + 1) * 32);
      wv[0] = wpp[0]; wv[1] = wpp[1];
    }
    {
      const short* Ac = ldsA[cur];
      const short* Bc = ldsB[cur];
      bf16x8 afr = *(const bf16x8*)&Ac[(klane * 128 + w * 16 + li) * 8];
#pragma unroll
      for (int fn = 0; fn < 8; ++fn) {
        bf16x8 bfr = *(const bf16x8*)&Bc[(klane * 128 + fn * 16 + li) * 8];
        acc[fn] = __builtin_amdgcn_mfma_f32_16x16x32_bf16(afr, bfr, acc[fn], 0, 0, 0);
      }
    }
    if (kt < 15) {
      const int nxt = cur ^ 1;
      const float* wf = (const float*)wv;
      bf16x8 vb, va;
#pragma unroll
      for (int j = 0; j < 8; ++j) {
        vb[j] = (short)f2bf(xv[j]);
        va[j] = (short)f2bf(wf[j]);
      }
      __syncthreads();
      *(bf16x8*)&ldsB[nxt][(fg * 128 + cm) * 8] = vb;
      *(bf16x8*)&ldsA[nxt][(fg * 128 + cm) * 8] = va;
      __syncthreads();
    }
  }

#pragma unroll
  for (int r = 0; r < 4; ++r) {
    const int g = g0 + w * 16 + klane * 4 + r;
    const size_t base = ((size_t)(b * 512 + g)) * 16384 + n0 + li;
    float xk[8];
#pragma unroll
    for (int k = 0; k < 8; ++k) xk[k] = x[base + (size_t)k * 2048];
    const float c0 = 12.f * xk[0] - 6.f * xk[4];
    const float c4 = 12.f * xk[4] - 6.f * xk[0];
    const float c1 = 6.f * xk[3];
    const float c2 = 6.f * xk[6];
    const float c3 = 6.f * xk[1];
    const float c5 = 6.f * xk[7];
    const float c6 = 6.f * xk[2];
    const float c7 = 6.f * xk[5];
    const float kf = c0 * acc[0][r] + c1 * acc[1][r]
                   + c2 * acc[2][r] + c3 * acc[3][r]
                   + c4 * acc[4][r] + c5 * acc[5][r]
                   + c6 * acc[6][r] + c7 * acc[7][r];
#pragma unroll
    for (int k = 0; k < 8; ++k) {
      const float o = (kf <= 0.f) ? xk[k] : fmaf(kf, acc[k][r], xk[k]);
      out[base + (size_t)k * 2048] = o;
    }
  }
}

extern "C" void kernel_launch(void* const* d_in, const int* in_sizes, int n_in,
                              void* d_out, int out_size, void* d_ws, size_t ws_size,
                              hipStream_t stream) {
  const float* x = (const float*)d_in[0];
  const float* W = (const float*)d_in[1];
  float* out = (float*)d_out;

  if (ws_size >= (size_t)524288) {
    short* wp = (short*)d_ws;                       // 512 KB packed W
    prepack_w<<<dim3(128), dim3(256), 0, stream>>>(W, wp);
    // 1024 blocks: 128 nt x 8 b ; 1024 thr (16 waves x 32 g-rows, full 512 g)
    lnkill_fullg4<<<dim3(1024), dim3(1024), 0, stream>>>(x, wp, out);
  } else {
    lnkill_fused<<<dim3(4096), dim3(512), 0, stream>>>(x, W, out);
  }
}